// Round 6
// baseline (34604.611 us; speedup 1.0000x reference)
//
#include <hip/hip_runtime.h>
#include <math.h>

// Echo-state network: sequential scan with dense 2048x2048 matvec per step.
// R6 design (changes from R5 marked NEW):
//  - Persistent scan: 128 blocks x 512 thr. Wave w owns rows R0=b*16+2w, R0+1;
//    lane l holds cols {4l+j+256m} of both rows as float4 w0q[8],w1q[8],
//    pinned via inline-asm (they live in AGPRs; VGPR_Count=52 is arch-VGPRs).
//  - h broadcast: block-cooperative poll of 2048 h words (4/thread, coalesced
//    stride-512) with straggler-only batched retry -> LDS tile, one barrier.
//  - NEW: x software-pipelined by ONE step. R5 issued x[t] at iteration top,
//    so the retry loop's s_waitcnt vmcnt(0) serialized a cold ~900cy x-miss
//    into EVERY step's detect. Now x[t+1] is issued after the barrier
//    (anchored between atomic poll and atomic store so it can't be hoisted
//    back into the retry window) and its latency hides under consume+detect.
//  - NEW: publish RAW biased values; the -2 un-bias is folded into a
//    precomputed per-lane correction (2*sum of W fragment) applied at acc
//    init -- removes 4 v_sub from the publish path.
//  - Sentinel sync: h stored biased +2 (ready iff >= 0.5); memset-0 and the
//    harness 0xAA poison (-3e-13) both read not-ready. No fences needed.
//  - fc1/fc2 collapse: M = fc2_w@fc1_w, c2 = fc2_w@fc1_b + fc2_b - 2*rowsum(M)
//    (the -2 un-biases stored states). Phase 3: GEMM states @ Mt(2048x64pad).

#define SS 16384
#define II 64
#define RR 2048
#define HH 128
#define OO 50
#define OP 64          // padded output dim
#define NBLK 128
#define NTHR 512
#define RPB 16         // rows per block (2 per wave)
#define TT 16          // timesteps per block in out_kernel

static const size_t STATES_BYTES = (size_t)SS * RR * 4;        // 134217728
static const size_t MT_BYTES     = (size_t)RR * OP * 4;        // 524288
static const size_t C2_OFF       = STATES_BYTES + MT_BYTES;
static const size_t RS_OFF       = C2_OFF + 256;
static const size_t WS_NEED      = RS_OFF + 512 + 256;

// Opaque register pin: forbids rematerialization/sinking of the value's def.
#define PIN4(q) asm volatile("" : "+v"((q).x), "+v"((q).y), "+v"((q).z), "+v"((q).w))

// ---------------------------------------------------------------------------
// Persistent scan kernel. Wave w of block b owns rows R0=b*16+2w, R0+1.
// ---------------------------------------------------------------------------
__global__ __launch_bounds__(NTHR, 2) __attribute__((amdgpu_waves_per_eu(2, 2)))
void scan_kernel(const float* __restrict__ x,
                 const float* __restrict__ Win,
                 const float* __restrict__ W,
                 float* __restrict__ states)
{
    const int tid  = threadIdx.x;
    const int blk  = blockIdx.x;
    const int wave = tid >> 6;              // 0..7
    const int lane = tid & 63;
    const int R0   = blk * RPB + wave * 2;

    // W fragments in registers/AGPRs; PIN4 prevents per-step refetch.
    float4 w0q[8], w1q[8];
#pragma unroll
    for (int m = 0; m < 8; ++m) {
        w0q[m] = *(const float4*)&W[(size_t)R0       * RR + 4 * lane + 256 * m];
        w1q[m] = *(const float4*)&W[(size_t)(R0 + 1) * RR + 4 * lane + 256 * m];
        PIN4(w0q[m]);
        PIN4(w1q[m]);
    }
    // Bias-fold constants: 2 * (sum of this lane's W fragment per row).
    float tw0 = 0.f, tw1 = 0.f;
#pragma unroll
    for (int m = 0; m < 8; ++m) {
        tw0 += w0q[m].x + w0q[m].y + w0q[m].z + w0q[m].w;
        tw1 += w1q[m].x + w1q[m].y + w1q[m].z + w1q[m].w;
    }
    tw0 *= 2.f; tw1 *= 2.f;

    // Input projection fragments (II == 64 == lanes)
    float win0 = Win[(size_t)R0       * II + lane];
    float win1 = Win[(size_t)(R0 + 1) * II + lane];
    asm volatile("" : "+v"(win0), "+v"(win1));

    __shared__ float hbuf[2][RR];   // double-buffered raw (biased) h tile

    const int   p    = lane & 1;    // even lanes track row R0, odd R0+1
    float       hold = 0.f;

    // x pipeline: preload step 0
    float xv = x[lane];

    for (int t = 0; t < SS; ++t) {
        float acc0 = win0 * xv;
        float acc1 = win1 * xv;
        float xn;                       // next step's x, issued mid-iteration

        if (t > 0) {
            const float* hp = states + (size_t)(t - 1) * RR;
            float* sb = hbuf[(t - 1) & 1];
            float v[4];
            // First pass: 4 coalesced loads/thread (block covers all 2048)
#pragma unroll
            for (int k = 0; k < 4; ++k)
                v[k] = __hip_atomic_load(hp + tid + 512 * k,
                                         __ATOMIC_RELAXED, __HIP_MEMORY_SCOPE_AGENT);
            // Straggler-only batched retry (exec-masked, 1 waitcnt/round)
            for (;;) {
                float mn = fminf(fminf(v[0], v[1]), fminf(v[2], v[3]));
                if (mn >= 0.5f) break;   // ready values are in (1,3)
#pragma unroll
                for (int k = 0; k < 4; ++k)
                    if (v[k] < 0.5f)
                        v[k] = __hip_atomic_load(hp + tid + 512 * k,
                                                 __ATOMIC_RELAXED, __HIP_MEMORY_SCOPE_AGENT);
            }
            // Publish RAW biased values (stride-512: 2-way bank alias, free)
#pragma unroll
            for (int k = 0; k < 4; ++k)
                sb[tid + 512 * k] = v[k];
            __syncthreads();           // the ONLY barrier per step

            // Issue next-step x HERE: after the retry loop (so its miss
            // latency is NOT inside this step's detect waitcnt), before the
            // consume/store (anchored by the volatile-op ordering below).
            {
                const int tn = (t + 1 < SS) ? (t + 1) : (SS - 1);
                xn = x[(size_t)tn * II + lane];
                asm volatile("" : "+v"(xn));
            }

            // Bias-fold: subtract 2*Sigma(w) once instead of un-biasing 2048
            // LDS values (butterfly sums the per-lane corrections to the full
            // row correction).
            acc0 -= tw0;
            acc1 -= tw1;

            // Consume: 8 x ds_read_b128, contiguous per lane (conflict-free)
            const float4* sq = (const float4*)sb;
#pragma unroll
            for (int m = 0; m < 8; ++m) {
                const float4 q = sq[lane + 64 * m];
                acc0 += w0q[m].x * q.x + w0q[m].y * q.y
                      + w0q[m].z * q.z + w0q[m].w * q.w;
                acc1 += w1q[m].x * q.x + w1q[m].y * q.y
                      + w1q[m].z * q.z + w1q[m].w * q.w;
            }
        } else {
            xn = x[II + lane];          // t=0: prefetch step 1
            asm volatile("" : "+v"(xn));
        }

        // Parity-combine then 5-level butterfly (6 shfls total):
        // even lanes end with full row-R0 sum, odd lanes with row-R0+1.
        {
            const float sel = p ? acc0 : acc1;     // the row NOT owned
            const float own = p ? acc1 : acc0;     // the row owned
            float a = own + __shfl_xor(sel, 1, 64);
#pragma unroll
            for (int off = 2; off <= 32; off <<= 1)
                a += __shfl_xor(a, off, 64);
            // tanh + leaky update for row R0+p
            float u = fminf(fmaxf(a, -20.f), 20.f);
            const float e  = __expf(2.f * u);
            const float th = (e - 1.f) / (e + 1.f);
            const float hn = 0.5f * hold + 0.5f * th;
            hold = hn;
            if (lane < 2)
                __hip_atomic_store(&states[(size_t)t * RR + R0 + lane], hn + 2.0f,
                                   __ATOMIC_RELAXED, __HIP_MEMORY_SCOPE_AGENT);
        }

        xv = xn;                        // rotate x pipeline
    }
}

// ---------------------------------------------------------------------------
// rowsum of fc1_w rows: rs[h] = sum_r fc1_w[h][r]
// ---------------------------------------------------------------------------
__global__ void k_rowsum(const float* __restrict__ fc1w, float* __restrict__ rs)
{
    const int h = blockIdx.x;
    const int tid = threadIdx.x;
    float a = 0.f;
    for (int r = tid; r < RR; r += 256) a += fc1w[(size_t)h * RR + r];
#pragma unroll
    for (int off = 1; off <= 32; off <<= 1) a += __shfl_xor(a, off, 64);
    __shared__ float red[4];
    if ((tid & 63) == 0) red[tid >> 6] = a;
    __syncthreads();
    if (tid == 0) rs[h] = red[0] + red[1] + red[2] + red[3];
}

// ---------------------------------------------------------------------------
// Mt[r][o] = sum_h fc2_w[o][h] * fc1_w[h][r]   (o padded to 64, zeros)
// ---------------------------------------------------------------------------
__global__ void k_mt(const float* __restrict__ fc1w,
                     const float* __restrict__ fc2w,
                     float* __restrict__ Mt)
{
    __shared__ float w2[OO][HH + 1];
    const int o = threadIdx.x;         // 64
    const int r = blockIdx.x;          // 2048
    for (int i = o; i < OO * HH; i += 64) w2[i / HH][i % HH] = fc2w[i];
    __syncthreads();
    float a = 0.f;
    if (o < OO) {
        for (int h = 0; h < HH; ++h)
            a += w2[o][h] * fc1w[(size_t)h * RR + r];
    }
    Mt[r * OP + o] = a;
}

// ---------------------------------------------------------------------------
// c2[o] = fc2_b[o] + sum_h fc2_w[o][h]*(fc1_b[h] - 2*rs[h])
// ---------------------------------------------------------------------------
__global__ void k_c2(const float* __restrict__ fc2w,
                     const float* __restrict__ fc2b,
                     const float* __restrict__ fc1b,
                     const float* __restrict__ rs,
                     float* __restrict__ c2)
{
    const int o = threadIdx.x;  // 64
    float a = 0.f;
    if (o < OO) {
        for (int h = 0; h < HH; ++h)
            a += fc2w[o * HH + h] * (fc1b[h] - 2.f * rs[h]);
        a += fc2b[o];
    }
    c2[o] = a;
}

// ---------------------------------------------------------------------------
// out[t][o] = sum_r Mt[r][o] * states_biased[t][r] + c2[o]
// ---------------------------------------------------------------------------
__global__ __launch_bounds__(256)
void out_kernel(const float* __restrict__ sb,
                const float* __restrict__ Mt,
                const float* __restrict__ c2,
                float* __restrict__ out)
{
    const int tid = threadIdx.x;
    const int o   = tid & 63;
    const int tl  = tid >> 6;          // 0..3
    const int t0  = blockIdx.x * TT;
    float acc[4] = {0.f, 0.f, 0.f, 0.f};
    const float* s0 = sb + (size_t)t0 * RR;

    for (int r = 0; r < RR; r += 4) {
        float4 sv0 = *(const float4*)(s0 + (size_t)(tl + 0)  * RR + r);
        float4 sv1 = *(const float4*)(s0 + (size_t)(tl + 4)  * RR + r);
        float4 sv2 = *(const float4*)(s0 + (size_t)(tl + 8)  * RR + r);
        float4 sv3 = *(const float4*)(s0 + (size_t)(tl + 12) * RR + r);
        float m0 = Mt[(r + 0) * OP + o];
        float m1 = Mt[(r + 1) * OP + o];
        float m2 = Mt[(r + 2) * OP + o];
        float m3 = Mt[(r + 3) * OP + o];
        acc[0] += m0 * sv0.x + m1 * sv0.y + m2 * sv0.z + m3 * sv0.w;
        acc[1] += m0 * sv1.x + m1 * sv1.y + m2 * sv1.z + m3 * sv1.w;
        acc[2] += m0 * sv2.x + m1 * sv2.y + m2 * sv2.z + m3 * sv2.w;
        acc[3] += m0 * sv3.x + m1 * sv3.y + m2 * sv3.z + m3 * sv3.w;
    }
    if (o < OO) {
        const float cc = c2[o];
#pragma unroll
        for (int m = 0; m < 4; ++m) {
            const int t = t0 + tl + 4 * m;
            out[(size_t)t * OO + o] = acc[m] + cc;
        }
    }
}

extern "C" void kernel_launch(void* const* d_in, const int* in_sizes, int n_in,
                              void* d_out, int out_size, void* d_ws, size_t ws_size,
                              hipStream_t stream)
{
    const float* x    = (const float*)d_in[0];
    const float* Win  = (const float*)d_in[1];
    const float* W    = (const float*)d_in[2];
    const float* fc1w = (const float*)d_in[3];
    const float* fc1b = (const float*)d_in[4];
    const float* fc2w = (const float*)d_in[5];
    const float* fc2b = (const float*)d_in[6];
    float* out = (float*)d_out;

    if (ws_size < WS_NEED) return;

    char*  ws     = (char*)d_ws;
    float* states = (float*)ws;
    float* Mt     = (float*)(ws + STATES_BYTES);
    float* c2     = (float*)(ws + C2_OFF);
    float* rs     = (float*)(ws + RS_OFF);

    // Sentinel init: 0.0f < 0.5f means "not ready" for every h value.
    hipMemsetAsync(states, 0, STATES_BYTES, stream);

    k_rowsum<<<HH, 256, 0, stream>>>(fc1w, rs);
    k_mt<<<RR, 64, 0, stream>>>(fc1w, fc2w, Mt);
    k_c2<<<1, 64, 0, stream>>>(fc2w, fc2b, fc1b, rs, c2);

    scan_kernel<<<NBLK, NTHR, 0, stream>>>(x, Win, W, states);

    out_kernel<<<SS / TT, 256, 0, stream>>>(states, Mt, c2, out);
}